// Round 5
// baseline (848.101 us; speedup 1.0000x reference)
//
#include <hip/hip_runtime.h>
#include <hip/hip_bf16.h>
#include <stdint.h>

#define DEV __device__ __forceinline__

typedef __attribute__((ext_vector_type(8))) short short8;
typedef __attribute__((ext_vector_type(4))) float f32x4;

#define B_ 2
#define S_ 4096
#define E_ 2048
#define H_ 16
#define D_ 128

DEV unsigned short f2bf(float x) {
  union { float f; uint32_t u; } a; a.f = x;
  uint32_t r = a.u + 0x7fffu + ((a.u >> 16) & 1u);
  return (unsigned short)(r >> 16);
}

DEV unsigned int cvt_pk_bf16(float a, float b) {
  unsigned int r;
  asm("v_cvt_pk_bf16_f32 %0, %1, %2" : "=v"(r) : "v"(a), "v"(b));
  return r;
}

DEV float exp2f_(float x) { return __builtin_amdgcn_exp2f(x); }

DEV void glds16(const void* g, void* l) {
  __builtin_amdgcn_global_load_lds(
      (const __attribute__((address_space(1))) uint32_t*)g,
      (__attribute__((address_space(3))) uint32_t*)l, 16, 0, 0);
}

__global__ __launch_bounds__(256) void cvtk(const float* __restrict__ in,
                                            unsigned short* __restrict__ out, int n4) {
  int i = blockIdx.x * blockDim.x + threadIdx.x;
  int stride = gridDim.x * blockDim.x;
  for (; i < n4; i += stride) {
    float4 v = ((const float4*)in)[i];
    ushort4 o;
    o.x = f2bf(v.x); o.y = f2bf(v.y); o.z = f2bf(v.z); o.w = f2bf(v.w);
    ((ushort4*)out)[i] = o;
  }
}

// C = A(MxK) * B(NxK)^T ; all bf16 inputs, fp32 accumulate.
template<int OUT_F32>
__global__ __launch_bounds__(256) void gemm_nt(
    const unsigned short* __restrict__ A,
    const unsigned short* __restrict__ Bm,
    void* __restrict__ Cp,
    const float* __restrict__ bias,
    int M, int N, int K, int nbn)
{
  __shared__ __align__(16) unsigned char lA[128 * 64];
  __shared__ __align__(16) unsigned char lB[128 * 64];
  int bid = blockIdx.x;
  int bm = bid / nbn, bn = bid % nbn;
  int t = threadIdx.x;
  int lane = t & 63, wv = t >> 6;
  int hi = lane >> 4, lo = lane & 15;
  int wm = wv >> 1, wn = wv & 1;
  int m0 = bm * 128, n0 = bn * 128;

  f32x4 acc[4][4] = {};

  for (int k0 = 0; k0 < K; k0 += 32) {
#pragma unroll
    for (int i = 0; i < 2; ++i) {
      int slot = i * 256 + t;
      int row = slot >> 2, c = slot & 3;
      int lbase = (i * 256 + wv * 64) * 16;
      glds16(A + (size_t)(m0 + row) * K + k0 + c * 8, lA + lbase);
      glds16(Bm + (size_t)(n0 + row) * K + k0 + c * 8, lB + lbase);
    }
    __syncthreads();
    short8 af[4], bfr[4];
#pragma unroll
    for (int mi = 0; mi < 4; ++mi)
      af[mi] = *(const short8*)(lA + (wm * 64 + mi * 16 + lo) * 64 + hi * 16);
#pragma unroll
    for (int nj = 0; nj < 4; ++nj)
      bfr[nj] = *(const short8*)(lB + (wn * 64 + nj * 16 + lo) * 64 + hi * 16);
#pragma unroll
    for (int mi = 0; mi < 4; ++mi)
#pragma unroll
      for (int nj = 0; nj < 4; ++nj)
        acc[mi][nj] = __builtin_amdgcn_mfma_f32_16x16x32_bf16(af[mi], bfr[nj], acc[mi][nj], 0, 0, 0);
    __syncthreads();
  }

  if constexpr (OUT_F32) {
    float* C = (float*)Cp;
#pragma unroll
    for (int mi = 0; mi < 4; ++mi)
#pragma unroll
      for (int nj = 0; nj < 4; ++nj) {
        int row = m0 + wm * 64 + mi * 16 + hi * 4;
        int col = n0 + wn * 64 + nj * 16 + lo;
        float bv = bias[col];
#pragma unroll
        for (int r = 0; r < 4; ++r)
          C[(size_t)(row + r) * N + col] = acc[mi][nj][r] + bv;
      }
  } else {
    unsigned short* C = (unsigned short*)Cp;
#pragma unroll
    for (int mi = 0; mi < 4; ++mi)
#pragma unroll
      for (int nj = 0; nj < 4; ++nj) {
        int row = m0 + wm * 64 + mi * 16 + hi * 4;
        int col = n0 + wn * 64 + nj * 16 + lo;
#pragma unroll
        for (int r = 0; r < 4; ++r)
          C[(size_t)(row + r) * N + col] = f2bf(acc[mi][nj][r]);
      }
  }
}

// vt[b,h,d,s] = qkv[b,s,2,h,d]
__global__ __launch_bounds__(256) void transpose_v(const unsigned short* __restrict__ qkv,
                                                   unsigned short* __restrict__ vt) {
  __shared__ __align__(16) unsigned char tl[32768];
  int bid = blockIdx.x;
  int st = bid & 31, bh = bid >> 5;
  int h = bh & 15, b = bh >> 4;
  int s0 = st * 128;
  int t = threadIdx.x, c = t & 15, rr = t >> 4;
#pragma unroll
  for (int i = 0; i < 8; ++i) {
    int s = rr + i * 16;
    const unsigned short* g = qkv + ((((size_t)b * S_ + s0 + s) * 3 + 2) * H_ + h) * D_ + c * 8;
    *(uint4*)(tl + s * 256 + ((c * 16) ^ (((s >> 3) & 7) << 4))) = *(const uint4*)g;
  }
  __syncthreads();
#pragma unroll
  for (int i = 0; i < 8; ++i) {
    int d = rr + i * 16;
    unsigned int w[4];
#pragma unroll
    for (int jj = 0; jj < 4; ++jj) {
      int s_a = c * 8 + jj * 2;
      unsigned int u0 = *(const unsigned short*)(tl + s_a * 256 + ((d * 2) ^ ((c & 7) << 4)));
      unsigned int u1 = *(const unsigned short*)(tl + (s_a + 1) * 256 + ((d * 2) ^ ((c & 7) << 4)));
      w[jj] = u0 | (u1 << 16);
    }
    uint4 val; val.x = w[0]; val.y = w[1]; val.z = w[2]; val.w = w[3];
    unsigned short* g = vt + (((size_t)b * H_ + h) * D_ + d) * S_ + s0 + c * 8;
    *(uint4*)g = val;
  }
}

// Flash attention, reference's extra l_ij semantics, KV block = 128.
// 4 waves x 32 q rows = 128-q block; LDS K/P 32K | V 32K = 64K -> 2 blocks/CU
// (2 waves/SIMD reg cap; two INDEPENDENT blocks overlap each other's stalls).
__global__ __launch_bounds__(256, 2) void attn_fwd(
    const unsigned short* __restrict__ qkv,  // [B,S,3,H,D] bf16
    const unsigned short* __restrict__ vt,   // [B,H,D,S] bf16
    unsigned short* __restrict__ abuf)       // [B,S,H*D] bf16
{
  __shared__ __align__(16) unsigned char lds[65536];
  unsigned char* lK = lds;           // K tile, then P (kv-halved), then epilogue
  unsigned char* lV = lds + 32768;

  // XCD-chunked swizzle: 1024 blocks, 8 XCDs, 128 consecutive logical blocks
  // per XCD -> the 32 q-blocks sharing one (b,h)'s K/V land on one XCD's L2.
  int bid = (blockIdx.x & 7) * 128 + (blockIdx.x >> 3);
  int qb = bid & 31, bh = bid >> 5;
  int h = bh & 15, b = bh >> 4;
  int t = threadIdx.x, lane = t & 63, wv = t >> 6;
  int hi = lane >> 4, lo = lane & 15;
  int q0 = qb * 128;
  const float c1 = 0.12751744f;  // (1/sqrt(128)) * log2(e)

  // Q fragments: 2 q sub-tiles (B-operand: col = q, k = d)
  short8 qf[2][4];
#pragma unroll
  for (int qj = 0; qj < 2; ++qj) {
    const unsigned short* qbase =
        qkv + ((((size_t)b * S_ + q0 + wv * 32 + qj * 16 + lo) * 3 + 0) * H_ + h) * D_;
#pragma unroll
    for (int ks = 0; ks < 4; ++ks)
      qf[qj][ks] = *(const short8*)(qbase + ks * 32 + hi * 8);
  }

  // staging: 256 threads stage 32KB K + 32KB V per iter in 8 groups of 16 rows.
  // Pre-swizzled global source, linear LDS dest. Per-thread swizzled column
  // offset is i/jb-invariant; per-group row offsets are compile-time.
  int sc = ((t & 15) * 16) ^ (((t >> 4) & 7) << 4);
  const unsigned char* gkb =
      (const unsigned char*)(qkv + (((size_t)b * S_ * 3 + 1) * H_ + h) * D_) +
      (size_t)(t >> 4) * 12288 + sc;
  const unsigned char* gvb =
      (const unsigned char*)(vt + ((size_t)b * H_ + h) * D_ * S_) +
      (size_t)(t >> 4) * 8192 + sc;
  unsigned char* lkd = lK + wv * 1024;
  unsigned char* lvd = lV + wv * 1024;

  f32x4 oacc[8][2] = {};  // out^T: d row = df*16+hi*4+r, q col = lo (per qj)
  float m_run[2] = {-__builtin_inff(), -__builtin_inff()};
  float l_run[2] = {0.f, 0.f};

  for (int jb = 0; jb < 32; ++jb) {
    size_t kvK = (size_t)jb * 1572864;  // 128 s-rows * 12288 B
    size_t kvV = (size_t)jb * 256;      // 128 kv cols * 2 B
#pragma unroll
    for (int i = 0; i < 8; ++i) {
      glds16(gkb + kvK + i * 196608, lkd + i * 4096);   // 16 K rows * 12288
      glds16(gvb + kvV + i * 131072, lvd + i * 4096);   // 16 V rows * 8192
    }
    __syncthreads();

    // S^T = K · Q^T
    f32x4 sacc[8][2] = {};
#pragma unroll
    for (int kf = 0; kf < 8; ++kf) {
      int kvr = kf * 16 + lo;
      int swz = (kvr & 7) << 4;
#pragma unroll
      for (int ks = 0; ks < 4; ++ks) {
        short8 kfr = *(const short8*)(lK + kvr * 256 + ((ks * 64 + hi * 16) ^ swz));
        sacc[kf][0] = __builtin_amdgcn_mfma_f32_16x16x32_bf16(kfr, qf[0][ks], sacc[kf][0], 0, 0, 0);
        sacc[kf][1] = __builtin_amdgcn_mfma_f32_16x16x32_bf16(kfr, qf[1][ks], sacc[kf][1], 0, 0, 0);
      }
    }

    // block softmax in log2 domain (per-lane q col = lo; hi replicas hold kv quarters)
    float m2[2], li[2], coef[2];
#pragma unroll
    for (int qj = 0; qj < 2; ++qj) {
      float mloc = -__builtin_inff();
#pragma unroll
      for (int kf = 0; kf < 8; ++kf)
#pragma unroll
        for (int r = 0; r < 4; ++r) mloc = fmaxf(mloc, sacc[kf][qj][r]);
      mloc = fmaxf(mloc, __shfl_xor(mloc, 16));
      mloc = fmaxf(mloc, __shfl_xor(mloc, 32));
      m2[qj] = mloc * c1;
      float lloc = 0.f;
#pragma unroll
      for (int kf = 0; kf < 8; ++kf)
#pragma unroll
        for (int r = 0; r < 4; ++r) {
          float p = exp2f_(fmaf(sacc[kf][qj][r], c1, -m2[qj]));
          sacc[kf][qj][r] = p;
          lloc += p;
        }
      lloc += __shfl_xor(lloc, 16);
      lloc += __shfl_xor(lloc, 32);
      li[qj] = lloc;  // = l_ij
    }

    if (__all(m2[0] <= m_run[0] && m2[1] <= m_run[1])) {
      // exact skip: m_new == m_run, alpha == 1
#pragma unroll
      for (int qj = 0; qj < 2; ++qj) {
        coef[qj] = exp2f_(m2[qj] - m_run[qj]) * li[qj];
        l_run[qj] += coef[qj];
      }
    } else {
      float alpha[2];
#pragma unroll
      for (int qj = 0; qj < 2; ++qj) {
        float mn = fmaxf(m_run[qj], m2[qj]);
        alpha[qj] = exp2f_(m_run[qj] - mn);
        coef[qj] = exp2f_(m2[qj] - mn) * li[qj];
        l_run[qj] = alpha[qj] * l_run[qj] + coef[qj];
        m_run[qj] = mn;
      }
#pragma unroll
      for (int df = 0; df < 8; ++df)
#pragma unroll
        for (int qj = 0; qj < 2; ++qj)
#pragma unroll
          for (int r = 0; r < 4; ++r) oacc[df][qj][r] *= alpha[qj];
    }

    __syncthreads();  // all waves done reading K before P overwrites its region

    // P (kv-halved) into the K region: rows rq in [0,128), 64 kv cols, 128B
    // stride, swizzled. Each wave touches only its own 32-row band -> the two
    // kv-halves need no inter-wave sync.
#pragma unroll
    for (int hf = 0; hf < 2; ++hf) {
#pragma unroll
      for (int qj = 0; qj < 2; ++qj) {
        int rq = wv * 32 + qj * 16 + lo;
        int swzq = (rq & 7) << 4;
        float cf = coef[qj];
#pragma unroll
        for (int kf = 4 * hf; kf < 4 * hf + 4; ++kf) {
          uint2 pk;
          pk.x = cvt_pk_bf16(sacc[kf][qj][0] * cf, sacc[kf][qj][1] * cf);
          pk.y = cvt_pk_bf16(sacc[kf][qj][2] * cf, sacc[kf][qj][3] * cf);
          *(uint2*)(lK + rq * 128 + ((((kf & 3) * 32) + hi * 8) ^ swzq)) = pk;
        }
      }
      asm volatile("" ::: "memory");  // order P writes before same-wave P reads

      // PV over this kv half: out^T += Vt · P^T
      {
        int rq0 = wv * 32 + lo, rq1 = rq0 + 16;
        int sz0 = (rq0 & 7) << 4;
#pragma unroll
        for (int ks = 2 * hf; ks < 2 * hf + 2; ++ks) {
          short8 pf0 = *(const short8*)(lK + rq0 * 128 + (((ks & 1) * 64 + hi * 16) ^ sz0));
          short8 pf1 = *(const short8*)(lK + rq1 * 128 + (((ks & 1) * 64 + hi * 16) ^ sz0));
#pragma unroll
          for (int df = 0; df < 8; ++df) {
            int dr = df * 16 + lo;
            short8 vf = *(const short8*)(lV + dr * 256 + ((ks * 64 + hi * 16) ^ ((dr & 7) << 4)));
            oacc[df][0] = __builtin_amdgcn_mfma_f32_16x16x32_bf16(vf, pf0, oacc[df][0], 0, 0, 0);
            oacc[df][1] = __builtin_amdgcn_mfma_f32_16x16x32_bf16(vf, pf1, oacc[df][1], 0, 0, 0);
          }
        }
      }
      asm volatile("" ::: "memory");  // P reads of this half before next half's writes
    }
    __syncthreads();  // all reads done before next stage overwrites lK/lV
  }

  // epilogue: out[q][d] = oacc^T / l_run, transpose via LDS, coalesced store
#pragma unroll
  for (int qj = 0; qj < 2; ++qj) {
    int rq = wv * 32 + qj * 16 + lo;
    int swzq = (rq & 7) << 4;
    float inv = 1.0f / l_run[qj];
#pragma unroll
    for (int df = 0; df < 8; ++df) {
      uint2 pk;
      pk.x = cvt_pk_bf16(oacc[df][qj][0] * inv, oacc[df][qj][1] * inv);
      pk.y = cvt_pk_bf16(oacc[df][qj][2] * inv, oacc[df][qj][3] * inv);
      *(uint2*)(lds + rq * 256 + ((df * 32 + hi * 8) ^ swzq)) = pk;
    }
  }
  __syncthreads();
#pragma unroll
  for (int i = 0; i < 8; ++i) {
    int row = i * 16 + (t >> 4);
    int c = t & 15;
    uint4 val = *(const uint4*)(lds + row * 256 + ((c * 16) ^ ((row & 7) << 4)));
    unsigned short* dst = abuf + (((size_t)b * S_ + q0 + row) * H_ + h) * D_ + c * 8;
    *(uint4*)dst = val;
  }
}

extern "C" void kernel_launch(void* const* d_in, const int* in_sizes, int n_in,
                              void* d_out, int out_size, void* d_ws, size_t ws_size,
                              hipStream_t stream) {
  const float* x = (const float*)d_in[0];
  const float* w_qkv = (const float*)d_in[1];
  const float* w_out = (const float*)d_in[2];
  const float* b_out = (const float*)d_in[3];
  float* out = (float*)d_out;
  char* ws = (char*)d_ws;

  unsigned short* xb    = (unsigned short*)(ws);
  unsigned short* wqkvb = (unsigned short*)(ws + 33554432);
  unsigned short* woutb = (unsigned short*)(ws + 58720256);
  unsigned short* qkvb  = (unsigned short*)(ws + 67108864);
  unsigned short* vtb   = (unsigned short*)(ws + 167772160);
  unsigned short* abuf  = xb;  // x dead after gemm1; reuse

  cvtk<<<2048, 256, 0, stream>>>(x, xb, (B_ * S_ * E_) / 4);
  cvtk<<<2048, 256, 0, stream>>>(w_qkv, wqkvb, (3 * E_ * E_) / 4);
  cvtk<<<1024, 256, 0, stream>>>(w_out, woutb, (E_ * E_) / 4);

  gemm_nt<0><<<64 * 48, 256, 0, stream>>>(xb, wqkvb, (void*)qkvb, nullptr,
                                          B_ * S_, 3 * E_, E_, 48);
  transpose_v<<<1024, 256, 0, stream>>>(qkvb, vtb);
  attn_fwd<<<1024, 256, 0, stream>>>(qkvb, vtb, abuf);
  gemm_nt<1><<<64 * 16, 256, 0, stream>>>(abuf, woutb, (void*)out, b_out,
                                          B_ * S_, E_, E_, 16);
}

// Round 6
// 779.168 us; speedup vs baseline: 1.0885x; 1.0885x over previous
//
#include <hip/hip_runtime.h>
#include <hip/hip_bf16.h>
#include <stdint.h>

#define DEV __device__ __forceinline__

typedef __attribute__((ext_vector_type(8))) short short8;
typedef __attribute__((ext_vector_type(4))) float f32x4;

#define B_ 2
#define S_ 4096
#define E_ 2048
#define H_ 16
#define D_ 128

DEV unsigned short f2bf(float x) {
  union { float f; uint32_t u; } a; a.f = x;
  uint32_t r = a.u + 0x7fffu + ((a.u >> 16) & 1u);
  return (unsigned short)(r >> 16);
}

DEV unsigned int cvt_pk_bf16(float a, float b) {
  unsigned int r;
  asm("v_cvt_pk_bf16_f32 %0, %1, %2" : "=v"(r) : "v"(a), "v"(b));
  return r;
}

DEV float exp2f_(float x) { return __builtin_amdgcn_exp2f(x); }

DEV void glds16(const void* g, void* l) {
  __builtin_amdgcn_global_load_lds(
      (const __attribute__((address_space(1))) uint32_t*)g,
      (__attribute__((address_space(3))) uint32_t*)l, 16, 0, 0);
}

__global__ __launch_bounds__(256) void cvtk(const float* __restrict__ in,
                                            unsigned short* __restrict__ out, int n4) {
  int i = blockIdx.x * blockDim.x + threadIdx.x;
  int stride = gridDim.x * blockDim.x;
  for (; i < n4; i += stride) {
    float4 v = ((const float4*)in)[i];
    ushort4 o;
    o.x = f2bf(v.x); o.y = f2bf(v.y); o.z = f2bf(v.z); o.w = f2bf(v.w);
    ((ushort4*)out)[i] = o;
  }
}

// C = A(MxK) * B(NxK)^T ; all bf16 inputs, fp32 accumulate.
template<int OUT_F32>
__global__ __launch_bounds__(256) void gemm_nt(
    const unsigned short* __restrict__ A,
    const unsigned short* __restrict__ Bm,
    void* __restrict__ Cp,
    const float* __restrict__ bias,
    int M, int N, int K, int nbn)
{
  __shared__ __align__(16) unsigned char lA[128 * 64];
  __shared__ __align__(16) unsigned char lB[128 * 64];
  int bid = blockIdx.x;
  int bm = bid / nbn, bn = bid % nbn;
  int t = threadIdx.x;
  int lane = t & 63, wv = t >> 6;
  int hi = lane >> 4, lo = lane & 15;
  int wm = wv >> 1, wn = wv & 1;
  int m0 = bm * 128, n0 = bn * 128;

  f32x4 acc[4][4] = {};

  for (int k0 = 0; k0 < K; k0 += 32) {
#pragma unroll
    for (int i = 0; i < 2; ++i) {
      int slot = i * 256 + t;
      int row = slot >> 2, c = slot & 3;
      int lbase = (i * 256 + wv * 64) * 16;
      glds16(A + (size_t)(m0 + row) * K + k0 + c * 8, lA + lbase);
      glds16(Bm + (size_t)(n0 + row) * K + k0 + c * 8, lB + lbase);
    }
    __syncthreads();
    short8 af[4], bfr[4];
#pragma unroll
    for (int mi = 0; mi < 4; ++mi)
      af[mi] = *(const short8*)(lA + (wm * 64 + mi * 16 + lo) * 64 + hi * 16);
#pragma unroll
    for (int nj = 0; nj < 4; ++nj)
      bfr[nj] = *(const short8*)(lB + (wn * 64 + nj * 16 + lo) * 64 + hi * 16);
#pragma unroll
    for (int mi = 0; mi < 4; ++mi)
#pragma unroll
      for (int nj = 0; nj < 4; ++nj)
        acc[mi][nj] = __builtin_amdgcn_mfma_f32_16x16x32_bf16(af[mi], bfr[nj], acc[mi][nj], 0, 0, 0);
    __syncthreads();
  }

  if constexpr (OUT_F32) {
    float* C = (float*)Cp;
#pragma unroll
    for (int mi = 0; mi < 4; ++mi)
#pragma unroll
      for (int nj = 0; nj < 4; ++nj) {
        int row = m0 + wm * 64 + mi * 16 + hi * 4;
        int col = n0 + wn * 64 + nj * 16 + lo;
        float bv = bias[col];
#pragma unroll
        for (int r = 0; r < 4; ++r)
          C[(size_t)(row + r) * N + col] = acc[mi][nj][r] + bv;
      }
  } else {
    unsigned short* C = (unsigned short*)Cp;
#pragma unroll
    for (int mi = 0; mi < 4; ++mi)
#pragma unroll
      for (int nj = 0; nj < 4; ++nj) {
        int row = m0 + wm * 64 + mi * 16 + hi * 4;
        int col = n0 + wn * 64 + nj * 16 + lo;
#pragma unroll
        for (int r = 0; r < 4; ++r)
          C[(size_t)(row + r) * N + col] = f2bf(acc[mi][nj][r]);
      }
  }
}

// vt[b,h,d,s] = qkv[b,s,2,h,d]
__global__ __launch_bounds__(256) void transpose_v(const unsigned short* __restrict__ qkv,
                                                   unsigned short* __restrict__ vt) {
  __shared__ __align__(16) unsigned char tl[32768];
  int bid = blockIdx.x;
  int st = bid & 31, bh = bid >> 5;
  int h = bh & 15, b = bh >> 4;
  int s0 = st * 128;
  int t = threadIdx.x, c = t & 15, rr = t >> 4;
#pragma unroll
  for (int i = 0; i < 8; ++i) {
    int s = rr + i * 16;
    const unsigned short* g = qkv + ((((size_t)b * S_ + s0 + s) * 3 + 2) * H_ + h) * D_ + c * 8;
    *(uint4*)(tl + s * 256 + ((c * 16) ^ (((s >> 3) & 7) << 4))) = *(const uint4*)g;
  }
  __syncthreads();
#pragma unroll
  for (int i = 0; i < 8; ++i) {
    int d = rr + i * 16;
    unsigned int w[4];
#pragma unroll
    for (int jj = 0; jj < 4; ++jj) {
      int s_a = c * 8 + jj * 2;
      unsigned int u0 = *(const unsigned short*)(tl + s_a * 256 + ((d * 2) ^ ((c & 7) << 4)));
      unsigned int u1 = *(const unsigned short*)(tl + (s_a + 1) * 256 + ((d * 2) ^ ((c & 7) << 4)));
      w[jj] = u0 | (u1 << 16);
    }
    uint4 val; val.x = w[0]; val.y = w[1]; val.z = w[2]; val.w = w[3];
    unsigned short* g = vt + (((size_t)b * H_ + h) * D_ + d) * S_ + s0 + c * 8;
    *(uint4*)g = val;
  }
}

// Flash attention, reference's extra l_ij semantics, KV block = 128.
// 8 waves x 32 q rows = 256-q block. K/V DOUBLE-buffered in LDS (2x64K=128K).
// Tile jb+1's staging issues at the top of iter jb; counted s_waitcnt vmcnt(8)
// + raw s_barrier keep the prefetch in flight across barriers (T3/T4).
__global__ __launch_bounds__(512, 2) void attn_fwd(
    const unsigned short* __restrict__ qkv,  // [B,S,3,H,D] bf16
    const unsigned short* __restrict__ vt,   // [B,H,D,S] bf16
    unsigned short* __restrict__ abuf)       // [B,S,H*D] bf16
{
  __shared__ __align__(16) unsigned char lds[131072];
  // buf n (n=0,1): K at n*65536, V at n*65536+32768

  // XCD-chunked swizzle: 512 blocks, 8 XCDs, 64 consecutive logical blocks per
  // XCD -> the 16 q-blocks sharing one (b,h)'s K/V land on the same XCD's L2.
  int bid = (blockIdx.x & 7) * 64 + (blockIdx.x >> 3);
  int qb = bid & 15, bh = bid >> 4;
  int h = bh & 15, b = bh >> 4;
  int t = threadIdx.x, lane = t & 63, wv = t >> 6;
  int hi = lane >> 4, lo = lane & 15;
  int q0 = qb * 256;
  const float c1 = 0.12751744f;  // (1/sqrt(128)) * log2(e)

  // Q fragments: 2 q sub-tiles (B-operand: col = q, k = d)
  short8 qf[2][4];
#pragma unroll
  for (int qj = 0; qj < 2; ++qj) {
    const unsigned short* qbase =
        qkv + ((((size_t)b * S_ + q0 + wv * 32 + qj * 16 + lo) * 3 + 0) * H_ + h) * D_;
#pragma unroll
    for (int ks = 0; ks < 4; ++ks)
      qf[qj][ks] = *(const short8*)(qbase + ks * 32 + hi * 8);
  }

  // staging pointers (pre-swizzled sources, linear LDS dest)
  const unsigned char* gk[4];
  const unsigned char* gv[4];
  int lbs[4];
  {
    int c = t & 15;
#pragma unroll
    for (int i = 0; i < 4; ++i) {
      int row = i * 32 + (t >> 4);
      int sw = (c * 16) ^ ((row & 7) << 4);
      gk[i] = (const unsigned char*)(qkv + ((((size_t)b * S_ + row) * 3 + 1) * H_ + h) * D_) + sw;
      gv[i] = (const unsigned char*)(vt + (((size_t)b * H_ + h) * D_ + row) * S_) + sw;
      lbs[i] = (i * 512 + wv * 64) * 16;
    }
  }

  f32x4 oacc[8][2] = {};  // out^T: d row = df*16+hi*4+r, q col = lo (per qj)
  float m_run[2] = {-__builtin_inff(), -__builtin_inff()};
  float l_run[2] = {0.f, 0.f};

  // prologue: stage tile 0 into buf 0
#pragma unroll
  for (int i = 0; i < 4; ++i) {
    glds16(gk[i], lds + lbs[i]);
    glds16(gv[i], lds + 32768 + lbs[i]);
  }

  for (int jb = 0; jb < 32; ++jb) {
    unsigned char* lK = lds + ((jb & 1) << 16);
    unsigned char* lV = lK + 32768;

    if (jb < 31) {
      // issue next tile's staging into the other buffer, then wait only for
      // the CURRENT tile's 8 loads (counted vmcnt leaves 8 in flight).
      size_t kvK = (size_t)(jb + 1) * 1572864;  // 128 s-rows * 12288 B
      size_t kvV = (size_t)(jb + 1) * 256;      // 128 kv cols * 2 B
      int lb = ((jb + 1) & 1) << 16;
#pragma unroll
      for (int i = 0; i < 4; ++i) {
        glds16(gk[i] + kvK, lds + lb + lbs[i]);
        glds16(gv[i] + kvV, lds + lb + 32768 + lbs[i]);
      }
      asm volatile("s_waitcnt vmcnt(8)" ::: "memory");
    } else {
      asm volatile("s_waitcnt vmcnt(0)" ::: "memory");
    }
    asm volatile("s_barrier" ::: "memory");  // current tile visible block-wide

    // S^T = K · Q^T
    f32x4 sacc[8][2] = {};
#pragma unroll
    for (int kf = 0; kf < 8; ++kf) {
      int kvr = kf * 16 + lo;
      int swz = (kvr & 7) << 4;
#pragma unroll
      for (int ks = 0; ks < 4; ++ks) {
        short8 kfr = *(const short8*)(lK + kvr * 256 + ((ks * 64 + hi * 16) ^ swz));
        sacc[kf][0] = __builtin_amdgcn_mfma_f32_16x16x32_bf16(kfr, qf[0][ks], sacc[kf][0], 0, 0, 0);
        sacc[kf][1] = __builtin_amdgcn_mfma_f32_16x16x32_bf16(kfr, qf[1][ks], sacc[kf][1], 0, 0, 0);
      }
    }

    // block softmax in log2 domain (per-lane q col = lo; hi replicas hold kv quarters)
    float m2[2], li[2], coef[2];
#pragma unroll
    for (int qj = 0; qj < 2; ++qj) {
      float mloc = -__builtin_inff();
#pragma unroll
      for (int kf = 0; kf < 8; ++kf)
#pragma unroll
        for (int r = 0; r < 4; ++r) mloc = fmaxf(mloc, sacc[kf][qj][r]);
      mloc = fmaxf(mloc, __shfl_xor(mloc, 16));
      mloc = fmaxf(mloc, __shfl_xor(mloc, 32));
      m2[qj] = mloc * c1;
      float lloc = 0.f;
#pragma unroll
      for (int kf = 0; kf < 8; ++kf)
#pragma unroll
        for (int r = 0; r < 4; ++r) {
          float p = exp2f_(fmaf(sacc[kf][qj][r], c1, -m2[qj]));
          sacc[kf][qj][r] = p;
          lloc += p;
        }
      lloc += __shfl_xor(lloc, 16);
      lloc += __shfl_xor(lloc, 32);
      li[qj] = lloc;  // = l_ij
    }

    if (__all(m2[0] <= m_run[0] && m2[1] <= m_run[1])) {
      // exact skip: m_new == m_run, alpha == 1
#pragma unroll
      for (int qj = 0; qj < 2; ++qj) {
        coef[qj] = exp2f_(m2[qj] - m_run[qj]) * li[qj];
        l_run[qj] += coef[qj];
      }
    } else {
      float alpha[2];
#pragma unroll
      for (int qj = 0; qj < 2; ++qj) {
        float mn = fmaxf(m_run[qj], m2[qj]);
        alpha[qj] = exp2f_(m_run[qj] - mn);
        coef[qj] = exp2f_(m2[qj] - mn) * li[qj];
        l_run[qj] = alpha[qj] * l_run[qj] + coef[qj];
        m_run[qj] = mn;
      }
#pragma unroll
      for (int df = 0; df < 8; ++df)
#pragma unroll
        for (int qj = 0; qj < 2; ++qj)
#pragma unroll
          for (int r = 0; r < 4; ++r) oacc[df][qj][r] *= alpha[qj];
    }

    // all waves done reading K (ds_reads consumed by MFMAs) before P overwrite;
    // raw barrier: prefetch loads to the other buffer stay in flight.
    asm volatile("s_barrier" ::: "memory");

    // P (kv-halved) into this buffer's K region: rows rq in [0,256), 64 kv
    // cols, 128B stride, swizzled. Wave-local 32-row bands -> no intra sync.
#pragma unroll
    for (int hf = 0; hf < 2; ++hf) {
#pragma unroll
      for (int qj = 0; qj < 2; ++qj) {
        int rq = wv * 32 + qj * 16 + lo;
        int swzq = (rq & 7) << 4;
        float cf = coef[qj];
#pragma unroll
        for (int kf = 4 * hf; kf < 4 * hf + 4; ++kf) {
          uint2 pk;
          pk.x = cvt_pk_bf16(sacc[kf][qj][0] * cf, sacc[kf][qj][1] * cf);
          pk.y = cvt_pk_bf16(sacc[kf][qj][2] * cf, sacc[kf][qj][3] * cf);
          *(uint2*)(lK + rq * 128 + ((((kf & 3) * 32) + hi * 8) ^ swzq)) = pk;
        }
      }
      asm volatile("" ::: "memory");  // order P writes before same-wave P reads

      // PV over this kv half: out^T += Vt · P^T
      {
        int rq0 = wv * 32 + lo, rq1 = rq0 + 16;
        int sz0 = (rq0 & 7) << 4;
#pragma unroll
        for (int ks = 2 * hf; ks < 2 * hf + 2; ++ks) {
          short8 pf0 = *(const short8*)(lK + rq0 * 128 + (((ks & 1) * 64 + hi * 16) ^ sz0));
          short8 pf1 = *(const short8*)(lK + rq1 * 128 + (((ks & 1) * 64 + hi * 16) ^ sz0));
#pragma unroll
          for (int df = 0; df < 8; ++df) {
            int dr = df * 16 + lo;
            short8 vf = *(const short8*)(lV + dr * 256 + ((ks * 64 + hi * 16) ^ ((dr & 7) << 4)));
            oacc[df][0] = __builtin_amdgcn_mfma_f32_16x16x32_bf16(vf, pf0, oacc[df][0], 0, 0, 0);
            oacc[df][1] = __builtin_amdgcn_mfma_f32_16x16x32_bf16(vf, pf1, oacc[df][1], 0, 0, 0);
          }
        }
      }
      asm volatile("" ::: "memory");  // P reads of this half before next half's writes
    }
    // all reads of this buffer done before iter jb+1 stages jb+2 into it.
    asm volatile("s_barrier" ::: "memory");
  }

  // epilogue: out[q][d] = oacc^T / l_run, transpose via lds[0..64K), coalesced store
#pragma unroll
  for (int qj = 0; qj < 2; ++qj) {
    int rq = wv * 32 + qj * 16 + lo;
    int swzq = (rq & 7) << 4;
    float inv = 1.0f / l_run[qj];
#pragma unroll
    for (int df = 0; df < 8; ++df) {
      uint2 pk;
      pk.x = cvt_pk_bf16(oacc[df][qj][0] * inv, oacc[df][qj][1] * inv);
      pk.y = cvt_pk_bf16(oacc[df][qj][2] * inv, oacc[df][qj][3] * inv);
      *(uint2*)(lds + rq * 256 + ((df * 32 + hi * 8) ^ swzq)) = pk;
    }
  }
  __syncthreads();
#pragma unroll
  for (int i = 0; i < 8; ++i) {
    int row = i * 32 + (t >> 4);
    int c = t & 15;
    uint4 val = *(const uint4*)(lds + row * 256 + ((c * 16) ^ ((row & 7) << 4)));
    unsigned short* dst = abuf + (((size_t)b * S_ + q0 + row) * H_ + h) * D_ + c * 8;
    *(uint4*)dst = val;
  }
}

extern "C" void kernel_launch(void* const* d_in, const int* in_sizes, int n_in,
                              void* d_out, int out_size, void* d_ws, size_t ws_size,
                              hipStream_t stream) {
  const float* x = (const float*)d_in[0];
  const float* w_qkv = (const float*)d_in[1];
  const float* w_out = (const float*)d_in[2];
  const float* b_out = (const float*)d_in[3];
  float* out = (float*)d_out;
  char* ws = (char*)d_ws;

  unsigned short* xb    = (unsigned short*)(ws);
  unsigned short* wqkvb = (unsigned short*)(ws + 33554432);
  unsigned short* woutb = (unsigned short*)(ws + 58720256);
  unsigned short* qkvb  = (unsigned short*)(ws + 67108864);
  unsigned short* vtb   = (unsigned short*)(ws + 167772160);
  unsigned short* abuf  = xb;  // x dead after gemm1; reuse

  cvtk<<<2048, 256, 0, stream>>>(x, xb, (B_ * S_ * E_) / 4);
  cvtk<<<2048, 256, 0, stream>>>(w_qkv, wqkvb, (3 * E_ * E_) / 4);
  cvtk<<<1024, 256, 0, stream>>>(w_out, woutb, (E_ * E_) / 4);

  gemm_nt<0><<<64 * 48, 256, 0, stream>>>(xb, wqkvb, (void*)qkvb, nullptr,
                                          B_ * S_, 3 * E_, E_, 48);
  transpose_v<<<1024, 256, 0, stream>>>(qkvb, vtb);
  attn_fwd<<<512, 512, 0, stream>>>(qkvb, vtb, abuf);
  gemm_nt<1><<<64 * 16, 256, 0, stream>>>(abuf, woutb, (void*)out, b_out,
                                          B_ * S_, E_, E_, 16);
}